// Round 8
// baseline (422.698 us; speedup 1.0000x reference)
//
#include <hip/hip_runtime.h>
#include <hip/hip_fp16.h>

#define N_NODES 100000
#define E_EDGES 1600000
#define F 256              // feature width at every stage
#define LV_OFF 12800000    // 100000*128
#define NBUK 782           // ceil(100000/128) dst-buckets of 128 nodes
#define EPB 8192           // edges per binning block
#define NBLK_BIN 196       // ceil(1.6M/8192)

typedef _Float16 half8 __attribute__((ext_vector_type(8)));
typedef _Float16 f16x4 __attribute__((ext_vector_type(4)));
typedef float    f32x4 __attribute__((ext_vector_type(4)));

__global__ void k_zero(int* __restrict__ p, int n) {
    int i = blockIdx.x * 256 + threadIdx.x;
    if (i < n) p[i] = 0;
}

// ---------------- fused: transpose weights to fp16 (256 blocks) + binA (196 blocks) ----------------
__global__ __launch_bounds__(256) void k_wprep_binA(
    const float* __restrict__ W1, const float* __restrict__ Wmu, const float* __restrict__ Wlv,
    _Float16* __restrict__ Wt1, _Float16* __restrict__ Wtc,
    const int* __restrict__ dst, int* __restrict__ gcnt, int* __restrict__ cbase)
{
    __shared__ int h[NBUK];
    int bid = blockIdx.x, tid = threadIdx.x;
    if (bid < 256) {
        int idx = bid * 256 + tid;   // 65536
        int n = idx >> 8, k = idx & 255;
        Wt1[n * 256 + k] = (_Float16)W1[k * 256 + n];
        float wc = (n < 128) ? Wmu[k * 128 + n] : Wlv[k * 128 + (n - 128)];
        Wtc[n * 256 + k] = (_Float16)wc;
        return;
    }
    int blk = bid - 256;             // 0..195
    for (int b = tid; b < NBUK; b += 256) h[b] = 0;
    __syncthreads();
    int e0 = blk * EPB, e1 = min(e0 + EPB, E_EDGES);
    for (int e = e0 + tid; e < e1; e += 256) atomicAdd(&h[dst[e] >> 7], 1);
    __syncthreads();
    for (int b = tid; b < NBUK; b += 256) {
        int c = h[b];
        cbase[blk * NBUK + b] = c ? atomicAdd(&gcnt[b], c) : 0;
    }
}

// ---------------- exclusive scan of 782 bucket counts ----------------
__global__ __launch_bounds__(1024) void k_scan782(const int* __restrict__ gcnt,
                                                  int* __restrict__ gbase) {
    __shared__ int sd[1024];
    int tid = threadIdx.x;
    int v = (tid < NBUK) ? gcnt[tid] : 0;
    sd[tid] = v;
    __syncthreads();
    for (int off = 1; off < 1024; off <<= 1) {
        int t = (tid >= off) ? sd[tid - off] : 0;
        __syncthreads();
        sd[tid] += t;
        __syncthreads();
    }
    if (tid < NBUK) gbase[tid] = sd[tid] - v;    // exclusive
    if (tid == NBUK - 1) gbase[NBUK] = sd[tid];  // total = E
}

// ---------------- binning pass D: per-bucket group-by-dst -> csr_src, row_off, dis ----------------
__global__ __launch_bounds__(256) void k_binD(const unsigned long long* __restrict__ ebuf,
                                              const int* __restrict__ gbase,
                                              int* __restrict__ csr_src, int* __restrict__ row_off,
                                              float* __restrict__ dis) {
    __shared__ int dh[128], dsc[128], dcur[128];
    int b = blockIdx.x, tid = threadIdx.x;
    if (tid < 128) dh[tid] = 0;
    __syncthreads();
    int s0 = gbase[b], s1 = gbase[b + 1];
    for (int i = s0 + tid; i < s1; i += 256)
        atomicAdd(&dh[(int)(ebuf[i] >> 32) & 127], 1);
    __syncthreads();
    if (tid < 128) dsc[tid] = dh[tid];
    __syncthreads();
    for (int off = 1; off < 128; off <<= 1) {
        int t = 0;
        if (tid < 128 && tid >= off) t = dsc[tid - off];
        __syncthreads();
        if (tid < 128) dsc[tid] += t;
        __syncthreads();
    }
    if (tid < 128) {
        int ex = dsc[tid] - dh[tid];   // exclusive within bucket
        dcur[tid] = ex;
        int node = b * 128 + tid;
        if (node < N_NODES) {
            row_off[node] = s0 + ex;
            dis[node] = rsqrtf((float)dh[tid] + 1.0f);
        }
    }
    if (b == 0 && tid == 128) row_off[N_NODES] = E_EDGES;
    __syncthreads();
    for (int i = s0 + tid; i < s1; i += 256) {
        unsigned long long ed = ebuf[i];
        int dl = (int)(ed >> 32) & 127;
        int lr = atomicAdd(&dcur[dl], 1);
        csr_src[s0 + lr] = (int)(ed & 0xFFFFFFFFull);
    }
}

// ---------------- fp16 MFMA GEMM tile body (NO dis scaling) ----------------
// A [M,256] row-major (fp32 or fp16); Bt fp16 [256n][256k] transposed; G fp16 [M,256].
template <typename TA>
__device__ __forceinline__ void gemm_tile(
    const TA* __restrict__ A, const _Float16* __restrict__ Bt,
    _Float16* __restrict__ G, int M, int m0, int tid, _Float16* Ah, _Float16* Bh)
{
    const int wave = tid >> 6, lane = tid & 63;
    const int wm   = wave & 1, wn = wave >> 1;      // 64-row half, 128-col half
    const int lrow = lane & 15, kgrp = lane >> 4;

    f32x4 acc[4][8];
#pragma unroll
    for (int i = 0; i < 4; i++)
#pragma unroll
        for (int j = 0; j < 8; j++) acc[i][j] = (f32x4){0.f, 0.f, 0.f, 0.f};

    for (int kt = 0; kt < 256; kt += 64) {
        // ---- stage A ----
        if constexpr (sizeof(TA) == 4) {
            const int sr = tid >> 4, kq = tid & 15;
#pragma unroll
            for (int p = 0; p < 8; ++p) {
                int row = p * 16 + sr;
                int gm = m0 + row; if (gm >= M) gm = M - 1;
                float4 v = *reinterpret_cast<const float4*>((const float*)A + (size_t)gm * F + kt + kq * 4);
                f16x4 h4;
                h4[0] = (_Float16)v.x; h4[1] = (_Float16)v.y;
                h4[2] = (_Float16)v.z; h4[3] = (_Float16)v.w;
                *reinterpret_cast<f16x4*>(&Ah[row * 64 + ((kq * 4) ^ ((row & 7) << 3))]) = h4;
            }
        } else {
#pragma unroll
            for (int p = 0; p < 4; ++p) {
                int u = p * 256 + tid;
                int row = u >> 3, slot = u & 7;
                int gm = m0 + row; if (gm >= M) gm = M - 1;
                half8 v = *reinterpret_cast<const half8*>((const _Float16*)A + (size_t)gm * F + kt + slot * 8);
                *reinterpret_cast<half8*>(&Ah[row * 64 + ((slot * 8) ^ ((row & 7) << 3))]) = v;
            }
        }
        // ---- stage B (full 256 cols) ----
#pragma unroll
        for (int p = 0; p < 8; ++p) {
            int u = p * 256 + tid;
            int n = u >> 3, slot = u & 7;
            half8 v = *reinterpret_cast<const half8*>(Bt + (size_t)n * F + kt + slot * 8);
            *reinterpret_cast<half8*>(&Bh[n * 64 + ((slot * 8) ^ ((n & 7) << 3))]) = v;
        }
        __syncthreads();
        // ---- compute: 2 k-substeps of 32 ----
#pragma unroll
        for (int ks = 0; ks < 2; ++ks) {
            int kk = ks * 32 + kgrp * 8;
            half8 ah[4], bh[8];
#pragma unroll
            for (int i = 0; i < 4; ++i) {
                int row = wm * 64 + i * 16 + lrow;
                ah[i] = *reinterpret_cast<const half8*>(&Ah[row * 64 + (kk ^ ((row & 7) << 3))]);
            }
#pragma unroll
            for (int j = 0; j < 8; ++j) {
                int col = wn * 128 + j * 16 + lrow;
                bh[j] = *reinterpret_cast<const half8*>(&Bh[col * 64 + (kk ^ ((col & 7) << 3))]);
            }
#pragma unroll
            for (int i = 0; i < 4; ++i)
#pragma unroll
                for (int j = 0; j < 8; ++j)
                    acc[i][j] = __builtin_amdgcn_mfma_f32_16x16x32_f16(ah[i], bh[j], acc[i][j], 0, 0, 0);
        }
        __syncthreads();
    }

    // ---- epilogue: C row = kgrp*4 + r, col = lrow ----
#pragma unroll
    for (int i = 0; i < 4; ++i) {
#pragma unroll
        for (int r = 0; r < 4; ++r) {
            int m = m0 + wm * 64 + i * 16 + kgrp * 4 + r;
            if (m >= M) continue;
#pragma unroll
            for (int j = 0; j < 8; ++j) {
                int n = wn * 128 + j * 16 + lrow;
                G[(size_t)m * F + n] = (_Float16)(acc[i][j][r]);
            }
        }
    }
}

// ---------------- fused: GEMM-1 (782 tiles) + binC (196 blocks), interleaved 4:1 ----------------
__global__ __launch_bounds__(256, 2) void k_gemm_binC(
    const float* __restrict__ A, const _Float16* __restrict__ Bt,
    _Float16* __restrict__ G, int M,
    const int* __restrict__ src, const int* __restrict__ dst,
    const int* __restrict__ gbase, const int* __restrict__ cbase,
    unsigned long long* __restrict__ ebuf)
{
    __shared__ _Float16 smem[128 * 64 + 256 * 64];   // 48 KB, reused by both roles
    int bid = blockIdx.x, tid = threadIdx.x;
    int r5 = bid % 5;
    if (r5 < 4) {
        int gid = (bid / 5) * 4 + r5;
        if (gid < 782)
            gemm_tile<float>(A, Bt, G, M, gid * 128, tid, smem, smem + 128 * 64);
        return;
    }
    // ---- binC role ----
    int* h2 = (int*)smem;          // [NBUK]
    int* bs = h2 + NBUK;           // [NBUK]
    int blk = bid / 5;             // 0..195
    for (int b = tid; b < NBUK; b += 256) {
        h2[b] = 0;
        bs[b] = gbase[b] + cbase[blk * NBUK + b];
    }
    __syncthreads();
    int e0 = blk * EPB, e1 = min(e0 + EPB, E_EDGES);
    for (int e = e0 + tid; e < e1; e += 256) {
        int d = dst[e];
        int b = d >> 7;
        int lr = atomicAdd(&h2[b], 1);
        ebuf[bs[b] + lr] = ((unsigned long long)(unsigned)d << 32) | (unsigned)src[e];
    }
}

// ---------------- standalone fp16 GEMM (layer 2) ----------------
__global__ __launch_bounds__(256, 2) void k_gemm_f16(
    const _Float16* __restrict__ A, const _Float16* __restrict__ Bt,
    _Float16* __restrict__ G, int M)
{
    __shared__ _Float16 smem[128 * 64 + 256 * 64];
    gemm_tile<_Float16>(A, Bt, G, M, blockIdx.x * 128, threadIdx.x, smem, smem + 128 * 64);
}

// ---------------- CSR gather v3: half-wave per row, 8-deep pipeline, dis[s] fma ----------------
// acc = dis[d]*g[d] + sum_s dis[s]*g[s];  epilogue applies dis[d] and bias.
template <int RELU>
__device__ __forceinline__ void aggregate_body(
    const _Float16* __restrict__ g, const int* __restrict__ row_off,
    const int* __restrict__ csr_src, const float* __restrict__ dis,
    const float* __restrict__ bmu, const float* __restrict__ blv,
    _Float16* __restrict__ hout, float* __restrict__ out)
{
    int d = blockIdx.x * 4 + (threadIdx.x >> 6);
    int lane = threadIdx.x & 63;
    int hf = lane >> 5, lp = lane & 31;
    const half8* g8 = reinterpret_cast<const half8*>(g);   // 32 half8 per row
    float dd = dis[d];
    float a0[8] = {0,0,0,0,0,0,0,0}, a1[8] = {0,0,0,0,0,0,0,0};
    float a2[8] = {0,0,0,0,0,0,0,0}, a3[8] = {0,0,0,0,0,0,0,0};
    if (hf == 0) {
        half8 sv = g8[(size_t)d * 32 + lp];
#pragma unroll
        for (int k = 0; k < 8; k++) a0[k] = dd * (float)sv[k];
    }
    int j0 = row_off[d], j1 = row_off[d + 1];
    int j = j0 + hf;
    // 8-deep main: 16 edges per iteration across both halves
    for (; j + 14 < j1; j += 16) {
        int s[8]; half8 v[8]; float dv[8];
#pragma unroll
        for (int p = 0; p < 8; ++p) s[p] = csr_src[j + 2 * p];
#pragma unroll
        for (int p = 0; p < 8; ++p) v[p] = g8[(size_t)s[p] * 32 + lp];
#pragma unroll
        for (int p = 0; p < 8; ++p) dv[p] = dis[s[p]];
#pragma unroll
        for (int k = 0; k < 8; k++) {
            a0[k] += dv[0] * (float)v[0][k]; a1[k] += dv[1] * (float)v[1][k];
            a2[k] += dv[2] * (float)v[2][k]; a3[k] += dv[3] * (float)v[3][k];
            a0[k] += dv[4] * (float)v[4][k]; a1[k] += dv[5] * (float)v[5][k];
            a2[k] += dv[6] * (float)v[6][k]; a3[k] += dv[7] * (float)v[7][k];
        }
    }
    // 2-deep mid tail
    for (; j + 2 < j1; j += 4) {
        int sA = csr_src[j], sB = csr_src[j + 2];
        half8 vA = g8[(size_t)sA * 32 + lp];
        half8 vB = g8[(size_t)sB * 32 + lp];
        float dA = dis[sA], dB = dis[sB];
#pragma unroll
        for (int k = 0; k < 8; k++) { a0[k] += dA * (float)vA[k]; a1[k] += dB * (float)vB[k]; }
    }
    // 1-deep tail
    if (j < j1) {
        int sA = csr_src[j];
        half8 vA = g8[(size_t)sA * 32 + lp];
        float dA = dis[sA];
#pragma unroll
        for (int k = 0; k < 8; k++) a0[k] += dA * (float)vA[k];
    }
#pragma unroll
    for (int k = 0; k < 8; k++) {
        a0[k] += a1[k] + a2[k] + a3[k];
        a0[k] += __shfl_xor(a0[k], 32);
    }
    if (RELU) {
        int c = lp * 8 + hf * 4;
        float4 bb = *reinterpret_cast<const float4*>(bmu + c);
        f16x4 o;
        o[0] = (_Float16)fmaxf(fmaf(dd, a0[hf * 4 + 0], bb.x), 0.0f);
        o[1] = (_Float16)fmaxf(fmaf(dd, a0[hf * 4 + 1], bb.y), 0.0f);
        o[2] = (_Float16)fmaxf(fmaf(dd, a0[hf * 4 + 2], bb.z), 0.0f);
        o[3] = (_Float16)fmaxf(fmaf(dd, a0[hf * 4 + 3], bb.w), 0.0f);
        *reinterpret_cast<f16x4*>(hout + (size_t)d * F + c) = o;
    } else {
        int ch = lp * 8 + hf * 4;                 // 0..252
        float va = a0[hf * 4 + 0], vb = a0[hf * 4 + 1], vc = a0[hf * 4 + 2], vd = a0[hf * 4 + 3];
        if (ch < 128) {
            float4 bb = *reinterpret_cast<const float4*>(bmu + ch);
            float4 o = make_float4(fmaf(dd, va, bb.x), fmaf(dd, vb, bb.y),
                                   fmaf(dd, vc, bb.z), fmaf(dd, vd, bb.w));
            *reinterpret_cast<float4*>(out + (size_t)d * 128 + ch) = o;
        } else {
            int c2 = ch - 128;
            float4 bb = *reinterpret_cast<const float4*>(blv + c2);
            float4 o = make_float4(fmaf(dd, va, bb.x), fmaf(dd, vb, bb.y),
                                   fmaf(dd, vc, bb.z), fmaf(dd, vd, bb.w));
            *reinterpret_cast<float4*>(out + LV_OFF + (size_t)d * 128 + c2) = o;
        }
    }
}

__global__ __launch_bounds__(256) void k_aggregate_relu(
    const _Float16* __restrict__ g, const int* __restrict__ row_off,
    const int* __restrict__ csr_src, const float* __restrict__ dis,
    const float* __restrict__ b, _Float16* __restrict__ h)
{
    aggregate_body<1>(g, row_off, csr_src, dis, b, nullptr, h, nullptr);
}

__global__ __launch_bounds__(256) void k_aggregate_out(
    const _Float16* __restrict__ g, const int* __restrict__ row_off,
    const int* __restrict__ csr_src, const float* __restrict__ dis,
    const float* __restrict__ bmu, const float* __restrict__ blv,
    float* __restrict__ out)
{
    aggregate_body<0>(g, row_off, csr_src, dis, bmu, blv, nullptr, out);
}

extern "C" void kernel_launch(void* const* d_in, const int* in_sizes, int n_in,
                              void* d_out, int out_size, void* d_ws, size_t ws_size,
                              hipStream_t stream) {
    const float* x   = (const float*)d_in[0];
    const int*   ei  = (const int*)d_in[1];
    const int*   src = ei;
    const int*   dst = ei + E_EDGES;
    const float* W1  = (const float*)d_in[2];
    const float* b1  = (const float*)d_in[3];
    const float* Wmu = (const float*)d_in[4];
    const float* bmu = (const float*)d_in[5];
    const float* Wlv = (const float*)d_in[6];
    const float* blv = (const float*)d_in[7];
    float* out = (float*)d_out;

    // workspace carve-up (1 KiB aligned)
    char* ws = (char*)d_ws;
    size_t o = 0;
    auto carve = [&](size_t bytes) -> char* {
        char* p = ws + o;
        o = (o + bytes + 1023) & ~(size_t)1023;
        return p;
    };
    float*    dis     = (float*)   carve(400000);
    int*      row_off = (int*)     carve(400004);
    int*      gcnt    = (int*)     carve(NBUK * 4);
    int*      gbase   = (int*)     carve((NBUK + 1) * 4);
    int*      cbase   = (int*)     carve((size_t)NBLK_BIN * NBUK * 4);   // 613 KB
    _Float16* Wt1     = (_Float16*)carve(131072);
    _Float16* Wtc     = (_Float16*)carve(131072);
    int*      csr_src = (int*)     carve((size_t)E_EDGES * 4);           // 6.4 MB
    unsigned long long* ebuf = (unsigned long long*)carve((size_t)E_EDGES * 8);  // 12.8 MB
    _Float16* g       = (_Float16*)carve((size_t)N_NODES * F * 2);       // 51.2 MB
    (void)ws_size;

    // h (fp16, 51.2 MB) lives in the upper half of d_out; dead before agg2's lv writes land
    _Float16* h16 = (_Float16*)(out + LV_OFF);

    // ---- pipeline ----
    k_zero      <<<(NBUK + 255) / 256, 256, 0, stream>>>(gcnt, NBUK);
    k_wprep_binA<<<256 + NBLK_BIN, 256, 0, stream>>>(W1, Wmu, Wlv, Wt1, Wtc, dst, gcnt, cbase);
    k_scan782   <<<1, 1024, 0, stream>>>(gcnt, gbase);
    // layer-1 GEMM (dis-free) fused with binC
    k_gemm_binC <<<980, 256, 0, stream>>>(x, Wt1, g, N_NODES, src, dst, gbase, cbase, ebuf);
    k_binD      <<<NBUK, 256, 0, stream>>>(ebuf, gbase, csr_src, row_off, dis);

    // layer 1 aggregate: h = fp16(relu(dis_d*(dis_d*g[d] + sum dis_s*g[s]) + b1))
    k_aggregate_relu<<<N_NODES / 4, 256, 0, stream>>>(g, row_off, csr_src, dis, b1, h16);

    // layer 2 (mu|lv fused)
    k_gemm_f16<<<782, 256, 0, stream>>>(h16, Wtc, g, N_NODES);
    k_aggregate_out<<<N_NODES / 4, 256, 0, stream>>>(g, row_off, csr_src, dis, bmu, blv, out);
}